// Round 4
// baseline (285.399 us; speedup 1.0000x reference)
//
#include <hip/hip_runtime.h>
#include <hip/hip_bf16.h>

#define NB   512   // sequence length N
#define DB   512   // model dim D
#define EB   64    // d_dir

typedef __bf16 bf16x8 __attribute__((ext_vector_type(8)));
typedef float  f32x4  __attribute__((ext_vector_type(4)));

// ---- Kernel A: q = t@Wq^T, k = t@Wk^T, rounded to bf16. 1 wave per (b,n). ----
__global__ __launch_bounds__(64) void qk_proj_bf16(
    const float* __restrict__ t,    // (B*N, 512)
    const float* __restrict__ Wq,   // (64, 512)
    const float* __restrict__ Wk,   // (64, 512)
    __bf16* __restrict__ qb,        // (B*N, 64)
    __bf16* __restrict__ kb)        // (B*N, 64)
{
    __shared__ float trow[DB];
    const int bn = blockIdx.x;
    const int e  = threadIdx.x;     // 0..63
    #pragma unroll
    for (int idx = 0; idx < DB / 64; ++idx)
        trow[idx * 64 + e] = t[(size_t)bn * DB + idx * 64 + e];
    __syncthreads();

    float aq = 0.f, ak = 0.f;
    const float* wqr = Wq + (size_t)e * DB;
    const float* wkr = Wk + (size_t)e * DB;
    #pragma unroll 8
    for (int d = 0; d < DB; ++d) {
        const float tv = trow[d];
        aq += tv * wqr[d];
        ak += tv * wkr[d];
    }
    qb[bn * EB + e] = (__bf16)aq;
    kb[bn * EB + e] = (__bf16)ak;
}

// ---- tiny: Wv fp32 -> bf16 ----
__global__ void wv_to_bf16(const float* __restrict__ Wv, __bf16* __restrict__ wvb, int n)
{
    int i = blockIdx.x * blockDim.x + threadIdx.x;
    if (i < n) wvb[i] = (__bf16)Wv[i];
}

// ---- Kernel B: out[b,i,j,d] = sum_e (k[b,j,e]*q[b,i,e]) * Wv[d,e] via MFMA ----
// grid = (D/128, N/128, B*N); block = 256 (4 waves). Wave w: j-rows [128*jt+32w, +32).
// MFMA operands SWAPPED vs R3: D^T = Wv_frag * kq_frag, so lane holds 4
// consecutive d at fixed j -> float4 stores (16 store instrs/wave, was 64).
__global__ __launch_bounds__(256) void kappa_mfma(
    const __bf16* __restrict__ qb,   // (B*N, 64)
    const __bf16* __restrict__ kb,   // (B*N, 64)
    const __bf16* __restrict__ wvb,  // (512, 64)  [d][e]
    float* __restrict__ out)         // (B*N, N, 512)
{
    const int dt = blockIdx.x;          // d-tile: 0..3  (128 cols)
    const int jt = blockIdx.y;          // j-tile: 0..3  (128 rows)
    const int bi = blockIdx.z;          // 0..B*N-1  (= b*N + i)
    const int b  = bi >> 9;             // bi / NB   (NB = 512)
    const int w  = threadIdx.x >> 6;    // wave 0..3
    const int l  = threadIdx.x & 63;    // lane
    const int lrow = l & 15;
    const int lgrp = l >> 4;            // k-base = lgrp*8
    const int jb = jt * 128 + w * 32;

    // Wv fragments (A operand after swap): lane holds row d = dt*128+df*16+lrow,
    // k-range e = ks*32 + lgrp*8 .. +8 -> contiguous 16B in the Wv row. L2-hit.
    bf16x8 bfrag[8][2];
    #pragma unroll
    for (int df = 0; df < 8; ++df) {
        const int d = dt * 128 + df * 16 + lrow;
        #pragma unroll
        for (int ks = 0; ks < 2; ++ks)
            bfrag[df][ks] = *reinterpret_cast<const bf16x8*>(
                wvb + (size_t)d * EB + ks * 32 + lgrp * 8);
    }

    // kq fragments (B operand after swap): A[j][e] = k[b,j,e] * q[b,i,e].
    bf16x8 afrag[2][2];
    #pragma unroll
    for (int ks = 0; ks < 2; ++ks) {
        const bf16x8 qv = *reinterpret_cast<const bf16x8*>(
            qb + (size_t)bi * EB + ks * 32 + lgrp * 8);
        #pragma unroll
        for (int jf = 0; jf < 2; ++jf) {
            const int j = jb + jf * 16 + lrow;
            const bf16x8 kv = *reinterpret_cast<const bf16x8*>(
                kb + ((size_t)b * NB + j) * EB + ks * 32 + lgrp * 8);
            bf16x8 a;
            #pragma unroll
            for (int x = 0; x < 8; ++x)
                a[x] = (__bf16)((float)kv[x] * (float)qv[x]);
            afrag[jf][ks] = a;
        }
    }

    // MFMA accumulate (operands swapped -> transposed output: m=d, n=j)
    f32x4 acc[2][8];
    #pragma unroll
    for (int jf = 0; jf < 2; ++jf)
        #pragma unroll
        for (int df = 0; df < 8; ++df) {
            acc[jf][df] = (f32x4){0.f, 0.f, 0.f, 0.f};
            acc[jf][df] = __builtin_amdgcn_mfma_f32_16x16x32_bf16(
                bfrag[df][0], afrag[jf][0], acc[jf][df], 0, 0, 0);
            acc[jf][df] = __builtin_amdgcn_mfma_f32_16x16x32_bf16(
                bfrag[df][1], afrag[jf][1], acc[jf][df], 0, 0, 0);
        }

    // Store: D^T layout -> col(lane&15) = j, row(lgrp*4+r) = d.
    // acc[r] = out[j][d0+r], r=0..3 -> one dwordx4 per fragment per lane.
    #pragma unroll
    for (int jf = 0; jf < 2; ++jf) {
        const int j = jb + jf * 16 + lrow;
        float* __restrict__ orow = out + ((size_t)bi * NB + j) * DB;
        #pragma unroll
        for (int df = 0; df < 8; ++df) {
            const int d0 = dt * 128 + df * 16 + lgrp * 4;
            *reinterpret_cast<f32x4*>(orow + d0) = acc[jf][df];
        }
    }
}

extern "C" void kernel_launch(void* const* d_in, const int* in_sizes, int n_in,
                              void* d_out, int out_size, void* d_ws, size_t ws_size,
                              hipStream_t stream) {
    const float* t  = (const float*)d_in[0];  // (2,512,512)
    const float* Wq = (const float*)d_in[1];  // (64,512)
    const float* Wk = (const float*)d_in[2];  // (64,512)
    const float* Wv = (const float*)d_in[3];  // (512,64)
    float* out = (float*)d_out;

    const int B = 2;

    __bf16* qb  = (__bf16*)d_ws;                       // B*N*64
    __bf16* kbf = qb + (size_t)B * NB * EB;            // B*N*64
    __bf16* wvb = kbf + (size_t)B * NB * EB;           // 512*64

    qk_proj_bf16<<<dim3(B * NB), dim3(64), 0, stream>>>(t, Wq, Wk, qb, kbf);
    wv_to_bf16<<<dim3((DB * EB + 255) / 256), dim3(256), 0, stream>>>(Wv, wvb, DB * EB);

    dim3 grid(DB / 128, NB / 128, B * NB);
    kappa_mfma<<<grid, dim3(256), 0, stream>>>(qb, kbf, wvb, out);
}

// Round 5
// 269.593 us; speedup vs baseline: 1.0586x; 1.0586x over previous
//
#include <hip/hip_runtime.h>
#include <hip/hip_bf16.h>

#define NB   512   // sequence length N
#define DB   512   // model dim D
#define EB   64    // d_dir
#define JTB  32    // j-rows per block
#define LSTR 520   // LDS row stride in floats (512 + 8 pad -> conflict-free)

typedef __bf16 bf16x8 __attribute__((ext_vector_type(8)));
typedef float  f32x4  __attribute__((ext_vector_type(4)));

// ---- Kernel A: q = t@Wq^T, k = t@Wk^T, rounded to bf16. 1 wave per (b,n). ----
__global__ __launch_bounds__(64) void qk_proj_bf16(
    const float* __restrict__ t,    // (B*N, 512)
    const float* __restrict__ Wq,   // (64, 512)
    const float* __restrict__ Wk,   // (64, 512)
    __bf16* __restrict__ qb,        // (B*N, 64)
    __bf16* __restrict__ kb)        // (B*N, 64)
{
    __shared__ float trow[DB];
    const int bn = blockIdx.x;
    const int e  = threadIdx.x;     // 0..63
    #pragma unroll
    for (int idx = 0; idx < DB / 64; ++idx)
        trow[idx * 64 + e] = t[(size_t)bn * DB + idx * 64 + e];
    __syncthreads();

    float aq = 0.f, ak = 0.f;
    const float* wqr = Wq + (size_t)e * DB;
    const float* wkr = Wk + (size_t)e * DB;
    #pragma unroll 8
    for (int d = 0; d < DB; ++d) {
        const float tv = trow[d];
        aq += tv * wqr[d];
        ak += tv * wkr[d];
    }
    qb[bn * EB + e] = (__bf16)aq;
    kb[bn * EB + e] = (__bf16)ak;
}

// ---- tiny: Wv fp32 -> bf16 ----
__global__ void wv_to_bf16(const float* __restrict__ Wv, __bf16* __restrict__ wvb, int n)
{
    int i = blockIdx.x * blockDim.x + threadIdx.x;
    if (i < n) wvb[i] = (__bf16)Wv[i];
}

// ---- Kernel B: out[b,i,j,d] = sum_e (k[b,j,e]*q[b,i,e]) * Wv[d,e] via MFMA ----
// grid = (N/32, B*N); block = 256 (4 waves). Block tile: 32 j-rows x all 512 d
// for one bi -> output tile is ONE contiguous 64KB range. Wave w owns d-quarter
// w*128. Epilogue: acc -> LDS [32][520] -> linear 1KB-per-wave-instr stores
// (the fillBuffer pattern that sustains 6.5 TB/s on this buffer).
__global__ __launch_bounds__(256) void kappa_mfma(
    const __bf16* __restrict__ qb,   // (B*N, 64)
    const __bf16* __restrict__ kb,   // (B*N, 64)
    const __bf16* __restrict__ wvb,  // (512, 64)  [d][e]
    float* __restrict__ out)         // (B*N, N, 512)
{
    const int jt = blockIdx.x;          // 0..15  (32-row j-tile)
    const int bi = blockIdx.y;          // 0..B*N-1  (= b*N + i)
    const int b  = bi >> 9;             // bi / NB
    const int w  = threadIdx.x >> 6;    // wave 0..3 -> d-quarter
    const int l  = threadIdx.x & 63;
    const int lrow = l & 15;
    const int lgrp = l >> 4;            // k-base = lgrp*8
    const int jb = jt * JTB;
    const int dbase = w * 128;

    __shared__ float tile[JTB * LSTR];  // 66,560 B -> 2 blocks/CU

    // Wv fragments (MFMA A operand): lane holds row d = dbase+df*16+lrow. L2-hit.
    bf16x8 bfrag[8][2];
    #pragma unroll
    for (int df = 0; df < 8; ++df) {
        const int d = dbase + df * 16 + lrow;
        #pragma unroll
        for (int ks = 0; ks < 2; ++ks)
            bfrag[df][ks] = *reinterpret_cast<const bf16x8*>(
                wvb + (size_t)d * EB + ks * 32 + lgrp * 8);
    }

    // kq fragments (MFMA B operand): A[j][e] = k[b,j,e] * q[b,i,e].
    bf16x8 afrag[2][2];
    #pragma unroll
    for (int ks = 0; ks < 2; ++ks) {
        const bf16x8 qv = *reinterpret_cast<const bf16x8*>(
            qb + (size_t)bi * EB + ks * 32 + lgrp * 8);
        #pragma unroll
        for (int jf = 0; jf < 2; ++jf) {
            const int j = jb + jf * 16 + lrow;
            const bf16x8 kv = *reinterpret_cast<const bf16x8*>(
                kb + ((size_t)b * NB + j) * EB + ks * 32 + lgrp * 8);
            bf16x8 a;
            #pragma unroll
            for (int x = 0; x < 8; ++x)
                a[x] = (__bf16)((float)kv[x] * (float)qv[x]);
            afrag[jf][ks] = a;
        }
    }

    // MFMA (swapped operands -> m=d, n=j): lane holds 4 consecutive d at fixed j.
    f32x4 acc[2][8];
    #pragma unroll
    for (int jf = 0; jf < 2; ++jf)
        #pragma unroll
        for (int df = 0; df < 8; ++df) {
            acc[jf][df] = (f32x4){0.f, 0.f, 0.f, 0.f};
            acc[jf][df] = __builtin_amdgcn_mfma_f32_16x16x32_bf16(
                bfrag[df][0], afrag[jf][0], acc[jf][df], 0, 0, 0);
            acc[jf][df] = __builtin_amdgcn_mfma_f32_16x16x32_bf16(
                bfrag[df][1], afrag[jf][1], acc[jf][df], 0, 0, 0);
        }

    // acc -> LDS: j = jf*16+lrow (local), d0 = dbase + df*16 + lgrp*4.
    // stride 520: banks spread, 8 lanes/bank-quad = floor, conflict-free.
    #pragma unroll
    for (int jf = 0; jf < 2; ++jf) {
        const int jl = jf * 16 + lrow;
        #pragma unroll
        for (int df = 0; df < 8; ++df) {
            const int d0 = dbase + df * 16 + lgrp * 4;
            *reinterpret_cast<f32x4*>(tile + jl * LSTR + d0) = acc[jf][df];
        }
    }
    __syncthreads();

    // Linear streaming store: 32x512 floats = contiguous 64KB at
    // out + (bi*NB + jb)*DB. 1KB contiguous per wave instruction.
    float* __restrict__ obase = out + ((size_t)bi * NB + jb) * DB;
    const int tid = threadIdx.x;
    #pragma unroll
    for (int p = 0; p < 16; ++p) {
        const int f = p * 1024 + tid * 4;     // flat float index in tile
        const int j = f >> 9;                  // local row
        const int d = f & 511;
        *reinterpret_cast<f32x4*>(obase + f) =
            *reinterpret_cast<const f32x4*>(tile + j * LSTR + d);
    }
}

extern "C" void kernel_launch(void* const* d_in, const int* in_sizes, int n_in,
                              void* d_out, int out_size, void* d_ws, size_t ws_size,
                              hipStream_t stream) {
    const float* t  = (const float*)d_in[0];  // (2,512,512)
    const float* Wq = (const float*)d_in[1];  // (64,512)
    const float* Wk = (const float*)d_in[2];  // (64,512)
    const float* Wv = (const float*)d_in[3];  // (512,64)
    float* out = (float*)d_out;

    const int B = 2;

    __bf16* qb  = (__bf16*)d_ws;                       // B*N*64
    __bf16* kbf = qb + (size_t)B * NB * EB;            // B*N*64
    __bf16* wvb = kbf + (size_t)B * NB * EB;           // 512*64

    qk_proj_bf16<<<dim3(B * NB), dim3(64), 0, stream>>>(t, Wq, Wk, qb, kbf);
    wv_to_bf16<<<dim3((DB * EB + 255) / 256), dim3(256), 0, stream>>>(Wv, wvb, DB * EB);

    dim3 grid(NB / JTB, B * NB);
    kappa_mfma<<<grid, dim3(256), 0, stream>>>(qb, kbf, wvb, out);
}

// Round 6
// 238.531 us; speedup vs baseline: 1.1965x; 1.1302x over previous
//
#include <hip/hip_runtime.h>
#include <hip/hip_bf16.h>

#define NB   512   // sequence length N
#define DB   512   // model dim D
#define EB   64    // d_dir
#define JT   16    // j-rows per tile
#define TPB  16    // tiles per block (block covers 256 rows = half a bi)

typedef __bf16 bf16x8 __attribute__((ext_vector_type(8)));
typedef float  f32x4  __attribute__((ext_vector_type(4)));

// ---- Kernel A: q = t@Wq^T, k = t@Wk^T, rounded to bf16. 1 wave per (b,n). ----
__global__ __launch_bounds__(64) void qk_proj_bf16(
    const float* __restrict__ t,    // (B*N, 512)
    const float* __restrict__ Wq,   // (64, 512)
    const float* __restrict__ Wk,   // (64, 512)
    __bf16* __restrict__ qb,        // (B*N, 64)
    __bf16* __restrict__ kb)        // (B*N, 64)
{
    __shared__ float trow[DB];
    const int bn = blockIdx.x;
    const int e  = threadIdx.x;     // 0..63
    #pragma unroll
    for (int idx = 0; idx < DB / 64; ++idx)
        trow[idx * 64 + e] = t[(size_t)bn * DB + idx * 64 + e];
    __syncthreads();

    float aq = 0.f, ak = 0.f;
    const float* wqr = Wq + (size_t)e * DB;
    const float* wkr = Wk + (size_t)e * DB;
    #pragma unroll 8
    for (int d = 0; d < DB; ++d) {
        const float tv = trow[d];
        aq += tv * wqr[d];
        ak += tv * wkr[d];
    }
    qb[bn * EB + e] = (__bf16)aq;
    kb[bn * EB + e] = (__bf16)ak;
}

// ---- tiny: Wv fp32 -> bf16 ----
__global__ void wv_to_bf16(const float* __restrict__ Wv, __bf16* __restrict__ wvb, int n)
{
    int i = blockIdx.x * blockDim.x + threadIdx.x;
    if (i < n) wvb[i] = (__bf16)Wv[i];
}

// ---- Kernel B (persistent): out[b,i,j,d] = sum_e (k[b,j,e]*q[b,i,e])*Wv[d,e] ----
// grid = 2048 blocks x 256 thr. Block blk: bi = blk>>1, j-rows [(blk&1)*256, +256)
// processed as 16 tiles of 16 rows x 512 d (32KB contiguous out per tile).
// Wv frags + q loaded ONCE; k rows prefetched one tile ahead; LDS 32KB with
// XOR-16B swizzle (conflict-free write AND read); stores = 1KB/wave-instr linear.
__global__ __launch_bounds__(256) void kappa_mfma(
    const __bf16* __restrict__ qb,   // (B*N, 64)
    const __bf16* __restrict__ kb,   // (B*N, 64)
    const __bf16* __restrict__ wvb,  // (512, 64)  [d][e]
    float* __restrict__ out)         // (B*N, N, 512)
{
    const int blk = blockIdx.x;          // 0..2047
    const int bi  = blk >> 1;            // 0..1023  (= b*N + i)
    const int b   = bi >> 9;             // batch
    const int jt0 = (blk & 1) * TPB;     // tile base within the bi
    const int w    = threadIdx.x >> 6;   // wave 0..3 -> d-quarter
    const int l    = threadIdx.x & 63;
    const int lrow = l & 15;
    const int lgrp = l >> 4;             // k-chunk base = lgrp*8
    const int dbase = w * 128;
    const int tid  = threadIdx.x;

    __shared__ float tile[JT * DB];      // exactly 32 KB

    // Wv fragments (MFMA A operand; swapped so m=d): loaded once. L2-hit.
    bf16x8 bfrag[8][2];
    #pragma unroll
    for (int df = 0; df < 8; ++df) {
        const int d = dbase + df * 16 + lrow;
        #pragma unroll
        for (int ks = 0; ks < 2; ++ks)
            bfrag[df][ks] = *reinterpret_cast<const bf16x8*>(
                wvb + (size_t)d * EB + ks * 32 + lgrp * 8);
    }

    // q chunks, loop-invariant
    const bf16x8 qv0 = *reinterpret_cast<const bf16x8*>(qb + (size_t)bi * EB + lgrp * 8);
    const bf16x8 qv1 = *reinterpret_cast<const bf16x8*>(qb + (size_t)bi * EB + 32 + lgrp * 8);

    const __bf16* __restrict__ kbase = kb + (size_t)b * NB * EB;

    // prefetch k-chunks for tile 0: row j = (jt0+t)*16 + lrow
    bf16x8 kv0 = *reinterpret_cast<const bf16x8*>(kbase + (size_t)(jt0 * JT + lrow) * EB + lgrp * 8);
    bf16x8 kv1 = *reinterpret_cast<const bf16x8*>(kbase + (size_t)(jt0 * JT + lrow) * EB + 32 + lgrp * 8);

    for (int t = 0; t < TPB; ++t) {
        // fold q into k  (a[e] = k[j,e]*q[i,e])
        bf16x8 a0, a1;
        #pragma unroll
        for (int x = 0; x < 8; ++x) {
            a0[x] = (__bf16)((float)kv0[x] * (float)qv0[x]);
            a1[x] = (__bf16)((float)kv1[x] * (float)qv1[x]);
        }

        // MFMA (swapped operands): acc[df][r] = out[j = jb+lrow][d = dbase+df*16+lgrp*4+r]
        f32x4 acc[8];
        #pragma unroll
        for (int df = 0; df < 8; ++df) {
            acc[df] = (f32x4){0.f, 0.f, 0.f, 0.f};
            acc[df] = __builtin_amdgcn_mfma_f32_16x16x32_bf16(bfrag[df][0], a0, acc[df], 0, 0, 0);
            acc[df] = __builtin_amdgcn_mfma_f32_16x16x32_bf16(bfrag[df][1], a1, acc[df], 0, 0, 0);
        }

        // prefetch k for next tile (uniform branch)
        if (t + 1 < TPB) {
            const int jn = (jt0 + t + 1) * JT + lrow;
            kv0 = *reinterpret_cast<const bf16x8*>(kbase + (size_t)jn * EB + lgrp * 8);
            kv1 = *reinterpret_cast<const bf16x8*>(kbase + (size_t)jn * EB + 32 + lgrp * 8);
        }

        __syncthreads();   // prior tile's LDS reads complete

        // acc -> LDS, XOR-16B swizzle: chunk = d/4, swz = chunk ^ (row&7)
        #pragma unroll
        for (int df = 0; df < 8; ++df) {
            const int chunk = w * 32 + df * 4 + lgrp;
            const int swz   = chunk ^ (lrow & 7);
            *reinterpret_cast<f32x4*>(tile + lrow * DB + swz * 4) = acc[df];
        }

        __syncthreads();

        // stream 32KB out: 8 passes x 1KB-contiguous per wave instruction
        float* __restrict__ obase = out + ((size_t)bi * NB + (size_t)(jt0 + t) * JT) * DB;
        #pragma unroll
        for (int p = 0; p < 8; ++p) {
            const int f = p * 1024 + tid * 4;       // flat float index in tile
            const int j = f >> 9;                   // row (uniform per wave-instr)
            const int dchunk = (f >> 2) & 127;
            const int swz = dchunk ^ (j & 7);
            *reinterpret_cast<f32x4*>(obase + f) =
                *reinterpret_cast<const f32x4*>(tile + j * DB + swz * 4);
        }
    }
}

extern "C" void kernel_launch(void* const* d_in, const int* in_sizes, int n_in,
                              void* d_out, int out_size, void* d_ws, size_t ws_size,
                              hipStream_t stream) {
    const float* t  = (const float*)d_in[0];  // (2,512,512)
    const float* Wq = (const float*)d_in[1];  // (64,512)
    const float* Wk = (const float*)d_in[2];  // (64,512)
    const float* Wv = (const float*)d_in[3];  // (512,64)
    float* out = (float*)d_out;

    const int B = 2;

    __bf16* qb  = (__bf16*)d_ws;                       // B*N*64
    __bf16* kbf = qb + (size_t)B * NB * EB;            // B*N*64
    __bf16* wvb = kbf + (size_t)B * NB * EB;           // 512*64

    qk_proj_bf16<<<dim3(B * NB), dim3(64), 0, stream>>>(t, Wq, Wk, qb, kbf);
    wv_to_bf16<<<dim3((DB * EB + 255) / 256), dim3(256), 0, stream>>>(Wv, wvb, DB * EB);

    kappa_mfma<<<dim3(2048), dim3(256), 0, stream>>>(qb, kbf, wvb, out);
}

// Round 7
// 234.530 us; speedup vs baseline: 1.2169x; 1.0171x over previous
//
#include <hip/hip_runtime.h>
#include <hip/hip_bf16.h>

#define NB   512   // sequence length N
#define DB   512   // model dim D
#define EB   64    // d_dir
#define JT   16    // j-rows per tile
#define TPB  16    // tiles per block (block covers 256 rows = half a bi)

typedef __bf16 bf16x8 __attribute__((ext_vector_type(8)));
typedef float  f32x4  __attribute__((ext_vector_type(4)));

// ---- Kernel A: q = t@Wq^T, k = t@Wk^T, rounded to bf16. 1 wave per (b,n). ----
__global__ __launch_bounds__(64) void qk_proj_bf16(
    const float* __restrict__ t,    // (B*N, 512)
    const float* __restrict__ Wq,   // (64, 512)
    const float* __restrict__ Wk,   // (64, 512)
    __bf16* __restrict__ qb,        // (B*N, 64)
    __bf16* __restrict__ kb)        // (B*N, 64)
{
    __shared__ float trow[DB];
    const int bn = blockIdx.x;
    const int e  = threadIdx.x;     // 0..63
    #pragma unroll
    for (int idx = 0; idx < DB / 64; ++idx)
        trow[idx * 64 + e] = t[(size_t)bn * DB + idx * 64 + e];
    __syncthreads();

    float aq = 0.f, ak = 0.f;
    const float* wqr = Wq + (size_t)e * DB;
    const float* wkr = Wk + (size_t)e * DB;
    #pragma unroll 8
    for (int d = 0; d < DB; ++d) {
        const float tv = trow[d];
        aq += tv * wqr[d];
        ak += tv * wkr[d];
    }
    qb[bn * EB + e] = (__bf16)aq;
    kb[bn * EB + e] = (__bf16)ak;
}

// ---- tiny: Wv fp32 -> bf16 ----
__global__ void wv_to_bf16(const float* __restrict__ Wv, __bf16* __restrict__ wvb, int n)
{
    int i = blockIdx.x * blockDim.x + threadIdx.x;
    if (i < n) wvb[i] = (__bf16)Wv[i];
}

// ---- Kernel B (persistent, barrier-free): ----
// out[b,i,j,d] = sum_e k[b,j,e] * (q[b,i,e] * Wv[d,e])
// q folded into Wv fragments ONCE per block -> per-tile work is pure
// {k-load, MFMA, LDS transpose, store}. Each wave owns a PRIVATE 8KB LDS
// region (XOR-swizzled, conflict-free both sides) -> NO __syncthreads at all;
// waves free-run so store issue stays continuous across the CU.
__global__ __launch_bounds__(256) void kappa_mfma(
    const __bf16* __restrict__ qb,   // (B*N, 64)
    const __bf16* __restrict__ kb,   // (B*N, 64)
    const __bf16* __restrict__ wvb,  // (512, 64)  [d][e]
    float* __restrict__ out)         // (B*N, N, 512)
{
    const int blk = blockIdx.x;          // 0..2047
    const int bi  = blk >> 1;            // 0..1023  (= b*N + i)
    const int b   = bi >> 9;             // batch
    const int jt0 = (blk & 1) * TPB;     // tile base within the bi
    const int w    = threadIdx.x >> 6;   // wave 0..3 -> d-quarter
    const int l    = threadIdx.x & 63;
    const int lrow = l & 15;
    const int lgrp = l >> 4;             // e-chunk base = lgrp*8
    const int dbase = w * 128;

    __shared__ float lds[4 * JT * 128];  // 32 KB total; 8 KB per wave
    float* __restrict__ wtile = lds + w * (JT * 128);

    // q chunks (loop-invariant)
    const bf16x8 qv0 = *reinterpret_cast<const bf16x8*>(qb + (size_t)bi * EB + lgrp * 8);
    const bf16x8 qv1 = *reinterpret_cast<const bf16x8*>(qb + (size_t)bi * EB + 32 + lgrp * 8);

    // Wv fragments with q FOLDED IN (once per block). m=d, lane lrow = d%16.
    bf16x8 bfrag[8][2];
    #pragma unroll
    for (int df = 0; df < 8; ++df) {
        const int d = dbase + df * 16 + lrow;
        #pragma unroll
        for (int ks = 0; ks < 2; ++ks) {
            const bf16x8 wv = *reinterpret_cast<const bf16x8*>(
                wvb + (size_t)d * EB + ks * 32 + lgrp * 8);
            const bf16x8 qq = ks ? qv1 : qv0;
            bf16x8 f;
            #pragma unroll
            for (int x = 0; x < 8; ++x)
                f[x] = (__bf16)((float)wv[x] * (float)qq[x]);
            bfrag[df][ks] = f;
        }
    }

    const __bf16* __restrict__ kbase = kb + (size_t)b * NB * EB;

    // prefetch k rows for tile 0 (B-operand: lane lrow = j%16, raw k, no VALU)
    bf16x8 kv0 = *reinterpret_cast<const bf16x8*>(kbase + (size_t)(jt0 * JT + lrow) * EB + lgrp * 8);
    bf16x8 kv1 = *reinterpret_cast<const bf16x8*>(kbase + (size_t)(jt0 * JT + lrow) * EB + 32 + lgrp * 8);

    const int r_lo = l >> 5;        // 0/1: epilogue row parity
    const int cc   = l & 31;        // epilogue d-chunk (16B units)

    for (int t = 0; t < TPB; ++t) {
        // MFMA: acc[df][r] = out[j=jb+lrow][d=dbase+df*16+lgrp*4+r]
        f32x4 acc[8];
        #pragma unroll
        for (int df = 0; df < 8; ++df) {
            acc[df] = (f32x4){0.f, 0.f, 0.f, 0.f};
            acc[df] = __builtin_amdgcn_mfma_f32_16x16x32_bf16(bfrag[df][0], kv0, acc[df], 0, 0, 0);
            acc[df] = __builtin_amdgcn_mfma_f32_16x16x32_bf16(bfrag[df][1], kv1, acc[df], 0, 0, 0);
        }

        // prefetch k for next tile (uniform branch)
        if (t + 1 < TPB) {
            const int jn = (jt0 + t + 1) * JT + lrow;
            kv0 = *reinterpret_cast<const bf16x8*>(kbase + (size_t)jn * EB + lgrp * 8);
            kv1 = *reinterpret_cast<const bf16x8*>(kbase + (size_t)jn * EB + 32 + lgrp * 8);
        }

        // acc -> wave-private LDS, XOR-16B swizzle: chunk c = df*4+lgrp,
        // sc = c ^ (row&7). Conflict-free (4 lanes/line, distinct quads).
        asm volatile("" ::: "memory");   // keep LDS ops ordered vs prior reads
        #pragma unroll
        for (int df = 0; df < 8; ++df) {
            const int sc = (df * 4 + lgrp) ^ (lrow & 7);
            *reinterpret_cast<f32x4*>(wtile + lrow * 128 + sc * 4) = acc[df];
        }
        asm volatile("" ::: "memory");   // writes before reads (in-order LDS pipe)

        // read back linear + store: per pass 64 lanes = 2 rows x 512B contiguous
        float* __restrict__ obase =
            out + ((size_t)bi * NB + (size_t)(jt0 + t) * JT) * DB + dbase;
        #pragma unroll
        for (int p = 0; p < 8; ++p) {
            const int r  = 2 * p + r_lo;
            const int sc = cc ^ (r & 7);
            const f32x4 v = *reinterpret_cast<const f32x4*>(wtile + r * 128 + sc * 4);
            *reinterpret_cast<f32x4*>(obase + (size_t)r * DB + cc * 4) = v;
        }
    }
}

extern "C" void kernel_launch(void* const* d_in, const int* in_sizes, int n_in,
                              void* d_out, int out_size, void* d_ws, size_t ws_size,
                              hipStream_t stream) {
    const float* t  = (const float*)d_in[0];  // (2,512,512)
    const float* Wq = (const float*)d_in[1];  // (64,512)
    const float* Wk = (const float*)d_in[2];  // (64,512)
    const float* Wv = (const float*)d_in[3];  // (512,64)
    float* out = (float*)d_out;

    const int B = 2;

    __bf16* qb  = (__bf16*)d_ws;                       // B*N*64
    __bf16* kbf = qb + (size_t)B * NB * EB;            // B*N*64
    __bf16* wvb = kbf + (size_t)B * NB * EB;           // 512*64

    qk_proj_bf16<<<dim3(B * NB), dim3(64), 0, stream>>>(t, Wq, Wk, qb, kbf);
    wv_to_bf16<<<dim3((DB * EB + 255) / 256), dim3(256), 0, stream>>>(Wv, wvb, DB * EB);

    kappa_mfma<<<dim3(2048), dim3(256), 0, stream>>>(qb, kbf, wvb, out);
}